// Round 3
// baseline (261.633 us; speedup 1.0000x reference)
//
#include <hip/hip_runtime.h>

#define NN 100000
#define NE 600000
#define DD 128

typedef _Float16 half4_t __attribute__((ext_vector_type(4)));
typedef _Float16 half8_t __attribute__((ext_vector_type(8)));
typedef float f32x4 __attribute__((ext_vector_type(4)));

// XOR-swizzle for [row][256B] f16 LDS tiles (G4). Byte address; flips bits
// 4-6 only, so 8B/16B alignment within a 16B slot is preserved.
__device__ __forceinline__ int swzb(int row, int byte) {
  return row * 256 + (byte ^ ((row & 7) << 4));
}

// ---------------------------------------------------------------------------
// edge_index dtype detection (int64 per reference vs int32 from default JAX).
// ---------------------------------------------------------------------------
__global__ void detect_idx64_kernel(const unsigned int* __restrict__ raw,
                                    int* __restrict__ flag) {
  if (threadIdx.x == 0 && blockIdx.x == 0) {
    int is64 = 1;
#pragma unroll 1
    for (int i = 0; i < 128; ++i) {
      if (raw[2 * i + 1] != 0u) { is64 = 0; break; }
    }
    *flag = is64;
  }
}

// ---------------------------------------------------------------------------
// Pack 5 weight matrices (128x128 f32, row-major [k][n]) into f16 fragment
// order: packed[m][(nf*4+ks)*64 + l][j] = W[8*(l>>4)+32*ks+j][16*nf+(l&15)].
// Validated in round 2 as the B-operand layout; reused here as the A-operand
// (W^T) layout for the swapped mfma(W_frag, data_frag) form.
// m: 0=W_src 1=W_tgt 2=W_proj[:128] 3=W_proj[128:] 4=W_mlp
// ---------------------------------------------------------------------------
__global__ void pack_weights_kernel(const float* __restrict__ Wsrc,
                                    const float* __restrict__ Wtgt,
                                    const float* __restrict__ Wproj,
                                    const float* __restrict__ Wmlp,
                                    _Float16* __restrict__ packed) {
  const int t = (int)blockIdx.x * 256 + (int)threadIdx.x;
  if (t >= 5 * 2048) return;
  const int m = t >> 11;
  const int rem = t & 2047;
  const int nf = rem >> 8;
  const int ks = (rem >> 6) & 3;
  const int l = rem & 63;
  const float* W;
  if (m == 0) W = Wsrc;
  else if (m == 1) W = Wtgt;
  else if (m == 2) W = Wproj;
  else if (m == 3) W = Wproj + 128 * DD;
  else W = Wmlp;
  const int col = (l & 15) + 16 * nf;
  const int k0 = 8 * (l >> 4) + 32 * ks;
  half8_t v;
#pragma unroll
  for (int j = 0; j < 8; ++j) v[j] = (_Float16)W[(size_t)(k0 + j) * DD + col];
  *reinterpret_cast<half8_t*>(packed + (size_t)m * 16384 + (size_t)rem * 8) = v;
}

// ---------------------------------------------------------------------------
// Phase 1: per-node tables (f16 out), swapped-operand MFMA, ZERO barriers.
//   A[n] = (sigmoid(x W_src) * x) @ W_proj[:128] + b_proj
//   B[n] = (sigmoid(x W_tgt) * x) @ W_proj[128:]
// 64 nodes/block, 4 waves; wave w owns nodes [w*16, w*16+16) (wave-private
// Ts tile -> no __syncthreads anywhere).
// Lane roles: lr=l&15 -> node (D col), lg=l>>4 -> k-chunk / wcol-quad.
// ---------------------------------------------------------------------------
__global__ __launch_bounds__(256)
void phase1_kernel(const float* __restrict__ Xg,
                   const _Float16* __restrict__ packW,
                   const float* __restrict__ bproj,
                   _Float16* __restrict__ Aout,
                   _Float16* __restrict__ Bout) {
  __shared__ _Float16 Ts[64 * DD];
  const int tid = (int)threadIdx.x;
  const int l = tid & 63;
  const int w = tid >> 6;
  const int lr = l & 15;
  const int lg = l >> 4;
  const int nloc = w * 16 + lr;                 // local node id
  const int row0 = (int)blockIdx.x * 64;
  const int ng = row0 + nloc;                   // global node id
  const bool valid = ng < NN;
  const int ngc = valid ? ng : (NN - 1);
  const float* __restrict__ xrow = Xg + (size_t)ngc * DD;

  // hoist the X B-fragments (X^T) across both passes: 32B contiguous / lane
  half8_t xf[4];
#pragma unroll
  for (int ks = 0; ks < 4; ++ks) {
    const f32x4 x0 = *reinterpret_cast<const f32x4*>(xrow + lg * 8 + ks * 32);
    const f32x4 x1 =
        *reinterpret_cast<const f32x4*>(xrow + lg * 8 + ks * 32 + 4);
    half8_t h;
#pragma unroll
    for (int j = 0; j < 4; ++j) {
      h[j] = (_Float16)x0[j];
      h[4 + j] = (_Float16)x1[j];
    }
    xf[ks] = h;
  }

#pragma unroll 1
  for (int p = 0; p < 2; ++p) {
    // ---- GEMM1: S^T = Wg^T X^T ----
    const _Float16* __restrict__ Wg = packW + (size_t)p * 16384;
    f32x4 acc[8];
#pragma unroll
    for (int nf = 0; nf < 8; ++nf) acc[nf] = (f32x4)0.f;
#pragma unroll
    for (int ks = 0; ks < 4; ++ks)
#pragma unroll
      for (int nf = 0; nf < 8; ++nf) {
        const half8_t wf = *reinterpret_cast<const half8_t*>(
            Wg + ((size_t)(nf * 4 + ks) * 64 + l) * 8);
        acc[nf] =
            __builtin_amdgcn_mfma_f32_16x16x32_f16(wf, xf[ks], acc[nf], 0, 0, 0);
      }

    // ---- T = sigmoid(S) * x  (lane holds S[node=ng][16nf+4lg .. +3]) ----
#pragma unroll
    for (int nf = 0; nf < 8; ++nf) {
      const int c0 = nf * 16 + lg * 4;
      const f32x4 x4 = *reinterpret_cast<const f32x4*>(xrow + c0);
      half4_t th;
#pragma unroll
      for (int j = 0; j < 4; ++j) {
        const float t = x4[j] / (1.f + __expf(-acc[nf][j]));
        th[j] = (_Float16)t;
      }
      *reinterpret_cast<half4_t*>(&Ts[swzb(nloc, c0 * 2) >> 1]) = th;
    }
    // wave-private Ts: compiler-inserted lgkmcnt orders write->read, no barrier

    // ---- GEMM2: table^T = Wp^T T^T ----
    const _Float16* __restrict__ Wp = packW + (size_t)(2 + p) * 16384;
    f32x4 acc2[8];
#pragma unroll
    for (int nf = 0; nf < 8; ++nf) acc2[nf] = (f32x4)0.f;
#pragma unroll
    for (int ks = 0; ks < 4; ++ks) {
      const half8_t tf = *reinterpret_cast<const half8_t*>(
          &Ts[swzb(nloc, lg * 16 + ks * 64) >> 1]);
#pragma unroll
      for (int nf = 0; nf < 8; ++nf) {
        const half8_t wf = *reinterpret_cast<const half8_t*>(
            Wp + ((size_t)(nf * 4 + ks) * 64 + l) * 8);
        acc2[nf] =
            __builtin_amdgcn_mfma_f32_16x16x32_f16(wf, tf, acc2[nf], 0, 0, 0);
      }
    }

    // ---- store: lane owns table[ng][16nf+4lg .. +3] -> half4 stores ----
    _Float16* __restrict__ dst = p ? Bout : Aout;
    if (valid) {
#pragma unroll
      for (int nf = 0; nf < 8; ++nf) {
        const int c0 = nf * 16 + lg * 4;
        f32x4 v = acc2[nf];
        if (p == 0) {
          const f32x4 bp = *reinterpret_cast<const f32x4*>(bproj + c0);
          v = v + bp;
        }
        half4_t h;
#pragma unroll
        for (int j = 0; j < 4; ++j) h[j] = (_Float16)v[j];
        *reinterpret_cast<half4_t*>(dst + (size_t)ng * DD + c0) = h;
      }
    }
  }
}

// ---------------------------------------------------------------------------
// Phase 2: out[e] = relu(A[src_e] + B[tgt_e]) @ W_mlp + b_mlp   (f32 out)
// Swapped-operand MFMA; direct global gather into B-fragments; NO LDS,
// NO barriers. 128 edges/block, 4 waves; wave w owns edges [w*32, w*32+32).
// ---------------------------------------------------------------------------
__global__ __launch_bounds__(256)
void phase2_kernel(const _Float16* __restrict__ At,
                   const _Float16* __restrict__ Bt,
                   const unsigned int* __restrict__ eraw,
                   const int* __restrict__ flag_p,
                   const _Float16* __restrict__ Wmlp_pk,
                   const float* __restrict__ bmlp,
                   float* __restrict__ out) {
  const int tid = (int)threadIdx.x;
  const int l = tid & 63;
  const int w = tid >> 6;
  const int lr = l & 15;
  const int lg = l >> 4;
  const int e0 = (int)blockIdx.x * 128 + w * 32;
  const int is64 = *flag_p;

  const int er0 = e0 + lr;        // mf = 0 edge
  const int er1 = e0 + 16 + lr;   // mf = 1 edge

  // gather table rows directly into B-fragments, relu(a+b) in registers
  half8_t rf[2][4];
#pragma unroll
  for (int mf = 0; mf < 2; ++mf) {
    const int e = mf ? er1 : er0;
    const size_t ec = (e < NE) ? (size_t)e : 0;
    int ia, ib;
    if (is64) {
      ia = (int)eraw[2 * ec];
      ib = (int)eraw[2 * ((size_t)NE + ec)];
    } else {
      ia = (int)eraw[ec];
      ib = (int)eraw[(size_t)NE + ec];
    }
    const _Float16* __restrict__ pa = At + (size_t)ia * DD + lg * 8;
    const _Float16* __restrict__ pb = Bt + (size_t)ib * DD + lg * 8;
#pragma unroll
    for (int ks = 0; ks < 4; ++ks) {
      const half8_t av = *reinterpret_cast<const half8_t*>(pa + ks * 32);
      const half8_t bv = *reinterpret_cast<const half8_t*>(pb + ks * 32);
      half8_t r;
#pragma unroll
      for (int j = 0; j < 8; ++j) {
        const _Float16 s = av[j] + bv[j];
        r[j] = s > (_Float16)0 ? s : (_Float16)0;
      }
      rf[mf][ks] = r;
    }
  }

  f32x4 acc[2][8];
#pragma unroll
  for (int mf = 0; mf < 2; ++mf)
#pragma unroll
    for (int nf = 0; nf < 8; ++nf) acc[mf][nf] = (f32x4)0.f;

#pragma unroll
  for (int ks = 0; ks < 4; ++ks)
#pragma unroll
    for (int nf = 0; nf < 8; ++nf) {
      const half8_t wf = *reinterpret_cast<const half8_t*>(
          Wmlp_pk + ((size_t)(nf * 4 + ks) * 64 + l) * 8);
      acc[0][nf] =
          __builtin_amdgcn_mfma_f32_16x16x32_f16(wf, rf[0][ks], acc[0][nf], 0, 0, 0);
      acc[1][nf] =
          __builtin_amdgcn_mfma_f32_16x16x32_f16(wf, rf[1][ks], acc[1][nf], 0, 0, 0);
    }

  // lane owns out[e][16nf+4lg .. +3] -> float4 nontemporal stores
#pragma unroll
  for (int nf = 0; nf < 8; ++nf) {
    const int c0 = nf * 16 + lg * 4;
    const f32x4 bm = *reinterpret_cast<const f32x4*>(bmlp + c0);
    if (er0 < NE) {
      const f32x4 v = acc[0][nf] + bm;
      __builtin_nontemporal_store(
          v, reinterpret_cast<f32x4*>(out + (size_t)er0 * DD + c0));
    }
    if (er1 < NE) {
      const f32x4 v = acc[1][nf] + bm;
      __builtin_nontemporal_store(
          v, reinterpret_cast<f32x4*>(out + (size_t)er1 * DD + c0));
    }
  }
}

// ---------------------------------------------------------------------------
extern "C" void kernel_launch(void* const* d_in, const int* in_sizes, int n_in,
                              void* d_out, int out_size, void* d_ws,
                              size_t ws_size, hipStream_t stream) {
  (void)in_sizes; (void)n_in; (void)out_size; (void)ws_size;

  const float* X = (const float*)d_in[0];
  const unsigned int* eraw = (const unsigned int*)d_in[1];
  const float* Wsrc = (const float*)d_in[2];
  const float* Wtgt = (const float*)d_in[3];
  const float* Wproj = (const float*)d_in[4];
  const float* bproj = (const float*)d_in[5];
  const float* Wmlp = (const float*)d_in[6];
  const float* bmlp = (const float*)d_in[7];
  float* out = (float*)d_out;

  // ws layout: A16[N*128] f16 | B16[N*128] f16 | packW[5*16384] f16 | flag
  _Float16* A16 = (_Float16*)d_ws;
  _Float16* B16 = A16 + (size_t)NN * DD;
  _Float16* packW = B16 + (size_t)NN * DD;
  int* flag = (int*)(packW + 5 * 16384);

  detect_idx64_kernel<<<1, 64, 0, stream>>>(eraw, flag);
  pack_weights_kernel<<<40, 256, 0, stream>>>(Wsrc, Wtgt, Wproj, Wmlp, packW);
  phase1_kernel<<<(NN + 63) / 64, 256, 0, stream>>>(X, packW, bproj, A16, B16);
  phase2_kernel<<<(NE + 127) / 128, 256, 0, stream>>>(A16, B16, eraw, flag,
                                                      packW + 4 * 16384, bmlp,
                                                      out);
}

// Round 4
// 218.112 us; speedup vs baseline: 1.1995x; 1.1995x over previous
//
#include <hip/hip_runtime.h>

#define NN 100000
#define NE 600000
#define DD 128

typedef _Float16 half4_t __attribute__((ext_vector_type(4)));
typedef _Float16 half8_t __attribute__((ext_vector_type(8)));
typedef float f32x4 __attribute__((ext_vector_type(4)));

// XOR-swizzle for [row][256B] f16 LDS tiles (G4). Byte address; flips bits
// 4-6 only, so 8B/16B alignment within a 16B slot is preserved.
__device__ __forceinline__ int swzb(int row, int byte) {
  return row * 256 + (byte ^ ((row & 7) << 4));
}

__device__ __forceinline__ half8_t relu_add(half8_t a, half8_t b) {
  half8_t r;
#pragma unroll
  for (int j = 0; j < 8; ++j) {
    const _Float16 s = a[j] + b[j];
    r[j] = s > (_Float16)0 ? s : (_Float16)0;
  }
  return r;
}

// ---------------------------------------------------------------------------
// Pack 5 weight matrices (128x128 f32, row-major [k][n]) into f16 fragment
// order: packed[m][(nf*4+ks)*64 + l][j] = W[8*(l>>4)+32*ks+j][16*nf+(l&15)].
// (Validated rounds 2-3 as both MFMA operand layouts.)
// Also detects edge_index dtype: wave 0 ballots over the first 64 odd words
// (int64 -> all zero; random int32 indices -> nonzero). flag=1 means int64.
// m: 0=W_src 1=W_tgt 2=W_proj[:128] 3=W_proj[128:] 4=W_mlp
// ---------------------------------------------------------------------------
__global__ void pack_weights_kernel(const float* __restrict__ Wsrc,
                                    const float* __restrict__ Wtgt,
                                    const float* __restrict__ Wproj,
                                    const float* __restrict__ Wmlp,
                                    const unsigned int* __restrict__ eraw,
                                    int* __restrict__ flag,
                                    _Float16* __restrict__ packed) {
  if (blockIdx.x == 0 && threadIdx.x < 64) {
    const unsigned long long b = __ballot(eraw[2 * threadIdx.x + 1] != 0u);
    if (threadIdx.x == 0) *flag = (b == 0ull) ? 1 : 0;
  }
  const int t = (int)blockIdx.x * 256 + (int)threadIdx.x;
  if (t >= 5 * 2048) return;
  const int m = t >> 11;
  const int rem = t & 2047;
  const int nf = rem >> 8;
  const int ks = (rem >> 6) & 3;
  const int l = rem & 63;
  const float* W;
  if (m == 0) W = Wsrc;
  else if (m == 1) W = Wtgt;
  else if (m == 2) W = Wproj;
  else if (m == 3) W = Wproj + 128 * DD;
  else W = Wmlp;
  const int col = (l & 15) + 16 * nf;
  const int k0 = 8 * (l >> 4) + 32 * ks;
  half8_t v;
#pragma unroll
  for (int j = 0; j < 8; ++j) v[j] = (_Float16)W[(size_t)(k0 + j) * DD + col];
  *reinterpret_cast<half8_t*>(packed + (size_t)m * 16384 + (size_t)rem * 8) = v;
}

// ---------------------------------------------------------------------------
// Phase 1: per-node tables (f16 out), swapped-operand MFMA, zero barriers.
//   A[n] = (sigmoid(x W_src) * x) @ W_proj[:128] + b_proj
//   B[n] = (sigmoid(x W_tgt) * x) @ W_proj[128:]
// 64 nodes/block, 4 waves; wave w owns nodes [w*16, w*16+16) (wave-private
// Ts tile). launch_bounds(...,4): cap VGPR at 128 for >=4 waves/SIMD.
// ---------------------------------------------------------------------------
__global__ __launch_bounds__(256, 4)
void phase1_kernel(const float* __restrict__ Xg,
                   const _Float16* __restrict__ packW,
                   const float* __restrict__ bproj,
                   _Float16* __restrict__ Aout,
                   _Float16* __restrict__ Bout) {
  __shared__ _Float16 Ts[64 * DD];
  const int tid = (int)threadIdx.x;
  const int l = tid & 63;
  const int w = tid >> 6;
  const int lr = l & 15;
  const int lg = l >> 4;
  const int nloc = w * 16 + lr;                 // local node id
  const int row0 = (int)blockIdx.x * 64;
  const int ng = row0 + nloc;                   // global node id
  const bool valid = ng < NN;
  const int ngc = valid ? ng : (NN - 1);
  const float* __restrict__ xrow = Xg + (size_t)ngc * DD;

  // hoist the X B-fragments (X^T) across both passes: 32B contiguous / lane
  half8_t xf[4];
#pragma unroll
  for (int ks = 0; ks < 4; ++ks) {
    const f32x4 x0 = *reinterpret_cast<const f32x4*>(xrow + lg * 8 + ks * 32);
    const f32x4 x1 =
        *reinterpret_cast<const f32x4*>(xrow + lg * 8 + ks * 32 + 4);
    half8_t h;
#pragma unroll
    for (int j = 0; j < 4; ++j) {
      h[j] = (_Float16)x0[j];
      h[4 + j] = (_Float16)x1[j];
    }
    xf[ks] = h;
  }

#pragma unroll 1
  for (int p = 0; p < 2; ++p) {
    // ---- GEMM1: S^T = Wg^T X^T ----
    const _Float16* __restrict__ wgb = packW + (size_t)p * 16384 + l * 8;
    f32x4 acc[8];
#pragma unroll
    for (int nf = 0; nf < 8; ++nf) acc[nf] = (f32x4)0.f;
#pragma unroll
    for (int ks = 0; ks < 4; ++ks)
#pragma unroll
      for (int nf = 0; nf < 8; ++nf) {
        const half8_t wf = *reinterpret_cast<const half8_t*>(
            wgb + (size_t)(nf * 4 + ks) * 512);
        acc[nf] =
            __builtin_amdgcn_mfma_f32_16x16x32_f16(wf, xf[ks], acc[nf], 0, 0, 0);
      }

    // ---- T = sigmoid(S) * x  (lane holds S[node=ng][16nf+4lg .. +3]) ----
#pragma unroll
    for (int nf = 0; nf < 8; ++nf) {
      const int c0 = nf * 16 + lg * 4;
      const f32x4 x4 = *reinterpret_cast<const f32x4*>(xrow + c0);
      half4_t th;
#pragma unroll
      for (int j = 0; j < 4; ++j) {
        const float t = x4[j] / (1.f + __expf(-acc[nf][j]));
        th[j] = (_Float16)t;
      }
      *reinterpret_cast<half4_t*>(&Ts[swzb(nloc, c0 * 2) >> 1]) = th;
    }
    // wave-private Ts: compiler-inserted lgkmcnt orders write->read, no barrier

    // ---- GEMM2: table^T = Wp^T T^T ----
    const _Float16* __restrict__ wpb = packW + (size_t)(2 + p) * 16384 + l * 8;
    f32x4 acc2[8];
#pragma unroll
    for (int nf = 0; nf < 8; ++nf) acc2[nf] = (f32x4)0.f;
#pragma unroll
    for (int ks = 0; ks < 4; ++ks) {
      const half8_t tf = *reinterpret_cast<const half8_t*>(
          &Ts[swzb(nloc, lg * 16 + ks * 64) >> 1]);
#pragma unroll
      for (int nf = 0; nf < 8; ++nf) {
        const half8_t wf = *reinterpret_cast<const half8_t*>(
            wpb + (size_t)(nf * 4 + ks) * 512);
        acc2[nf] =
            __builtin_amdgcn_mfma_f32_16x16x32_f16(wf, tf, acc2[nf], 0, 0, 0);
      }
    }

    // ---- store: lane owns table[ng][16nf+4lg .. +3] -> half4 stores ----
    _Float16* __restrict__ dst = p ? Bout : Aout;
    if (valid) {
#pragma unroll
      for (int nf = 0; nf < 8; ++nf) {
        const int c0 = nf * 16 + lg * 4;
        f32x4 v = acc2[nf];
        if (p == 0) {
          const f32x4 bp = *reinterpret_cast<const f32x4*>(bproj + c0);
          v = v + bp;
        }
        half4_t h;
#pragma unroll
        for (int j = 0; j < 4; ++j) h[j] = (_Float16)v[j];
        *reinterpret_cast<half4_t*>(dst + (size_t)ng * DD + c0) = h;
      }
    }
  }
}

// ---------------------------------------------------------------------------
// Phase 2: out[e] = relu(A[src_e] + B[tgt_e]) @ W_mlp + b_mlp   (f32 out)
// Swapped-operand MFMA; direct global gather, software-pipelined over ks so
// peak regs ~= acc 64 + cur 16 + next 16 -> fits the 128-VGPR / 4-wave cap.
// 128 edges/block, 4 waves; wave w owns edges [w*32, w*32+32). No LDS.
// ---------------------------------------------------------------------------
__global__ __launch_bounds__(256, 4)
void phase2_kernel(const _Float16* __restrict__ At,
                   const _Float16* __restrict__ Bt,
                   const unsigned int* __restrict__ eraw,
                   const int* __restrict__ flag_p,
                   const _Float16* __restrict__ Wpk,
                   const float* __restrict__ bmlp,
                   float* __restrict__ out) {
  const int tid = (int)threadIdx.x;
  const int l = tid & 63;
  const int w = tid >> 6;
  const int lr = l & 15;
  const int lg = l >> 4;
  const int e0 = (int)blockIdx.x * 128 + w * 32;
  const int is64 = *flag_p;

  const int er0 = e0 + lr;        // mf = 0 edge
  const int er1 = e0 + 16 + lr;   // mf = 1 edge
  const size_t ec0 = (er0 < NE) ? (size_t)er0 : 0;
  const size_t ec1 = (er1 < NE) ? (size_t)er1 : 0;

  int ia0, ib0, ia1, ib1;
  if (is64) {
    ia0 = (int)eraw[2 * ec0];
    ib0 = (int)eraw[2 * ((size_t)NE + ec0)];
    ia1 = (int)eraw[2 * ec1];
    ib1 = (int)eraw[2 * ((size_t)NE + ec1)];
  } else {
    ia0 = (int)eraw[ec0];
    ib0 = (int)eraw[(size_t)NE + ec0];
    ia1 = (int)eraw[ec1];
    ib1 = (int)eraw[(size_t)NE + ec1];
  }
  const _Float16* __restrict__ pa0 = At + (size_t)ia0 * DD + lg * 8;
  const _Float16* __restrict__ pb0 = Bt + (size_t)ib0 * DD + lg * 8;
  const _Float16* __restrict__ pa1 = At + (size_t)ia1 * DD + lg * 8;
  const _Float16* __restrict__ pb1 = Bt + (size_t)ib1 * DD + lg * 8;
  const _Float16* __restrict__ wbase = Wpk + l * 8;

  f32x4 acc[2][8];
#pragma unroll
  for (int mf = 0; mf < 2; ++mf)
#pragma unroll
    for (int nf = 0; nf < 8; ++nf) acc[mf][nf] = (f32x4)0.f;

  // prologue gather (ks = 0)
  half8_t a0 = *reinterpret_cast<const half8_t*>(pa0);
  half8_t b0 = *reinterpret_cast<const half8_t*>(pb0);
  half8_t a1 = *reinterpret_cast<const half8_t*>(pa1);
  half8_t b1 = *reinterpret_cast<const half8_t*>(pb1);

#pragma unroll
  for (int ks = 0; ks < 4; ++ks) {
    half8_t na0, nb0, na1, nb1;
    if (ks < 3) {  // prefetch next ks gathers under this ks's MFMAs
      na0 = *reinterpret_cast<const half8_t*>(pa0 + (ks + 1) * 32);
      nb0 = *reinterpret_cast<const half8_t*>(pb0 + (ks + 1) * 32);
      na1 = *reinterpret_cast<const half8_t*>(pa1 + (ks + 1) * 32);
      nb1 = *reinterpret_cast<const half8_t*>(pb1 + (ks + 1) * 32);
    }
    const half8_t r0 = relu_add(a0, b0);
    const half8_t r1 = relu_add(a1, b1);
#pragma unroll
    for (int nf = 0; nf < 8; ++nf) {
      const half8_t wf = *reinterpret_cast<const half8_t*>(
          wbase + (size_t)(nf * 4 + ks) * 512);
      acc[0][nf] =
          __builtin_amdgcn_mfma_f32_16x16x32_f16(wf, r0, acc[0][nf], 0, 0, 0);
      acc[1][nf] =
          __builtin_amdgcn_mfma_f32_16x16x32_f16(wf, r1, acc[1][nf], 0, 0, 0);
    }
    if (ks < 3) { a0 = na0; b0 = nb0; a1 = na1; b1 = nb1; }
  }

  // lane owns out[e][16nf+4lg .. +3] -> float4 nontemporal stores
#pragma unroll
  for (int nf = 0; nf < 8; ++nf) {
    const int c0 = nf * 16 + lg * 4;
    const f32x4 bm = *reinterpret_cast<const f32x4*>(bmlp + c0);
    if (er0 < NE) {
      const f32x4 v = acc[0][nf] + bm;
      __builtin_nontemporal_store(
          v, reinterpret_cast<f32x4*>(out + (size_t)er0 * DD + c0));
    }
    if (er1 < NE) {
      const f32x4 v = acc[1][nf] + bm;
      __builtin_nontemporal_store(
          v, reinterpret_cast<f32x4*>(out + (size_t)er1 * DD + c0));
    }
  }
}

// ---------------------------------------------------------------------------
extern "C" void kernel_launch(void* const* d_in, const int* in_sizes, int n_in,
                              void* d_out, int out_size, void* d_ws,
                              size_t ws_size, hipStream_t stream) {
  (void)in_sizes; (void)n_in; (void)out_size; (void)ws_size;

  const float* X = (const float*)d_in[0];
  const unsigned int* eraw = (const unsigned int*)d_in[1];
  const float* Wsrc = (const float*)d_in[2];
  const float* Wtgt = (const float*)d_in[3];
  const float* Wproj = (const float*)d_in[4];
  const float* bproj = (const float*)d_in[5];
  const float* Wmlp = (const float*)d_in[6];
  const float* bmlp = (const float*)d_in[7];
  float* out = (float*)d_out;

  // ws layout: A16[N*128] f16 | B16[N*128] f16 | packW[5*16384] f16 | flag
  _Float16* A16 = (_Float16*)d_ws;
  _Float16* B16 = A16 + (size_t)NN * DD;
  _Float16* packW = B16 + (size_t)NN * DD;
  int* flag = (int*)(packW + 5 * 16384);

  pack_weights_kernel<<<40, 256, 0, stream>>>(Wsrc, Wtgt, Wproj, Wmlp, eraw,
                                              flag, packW);
  phase1_kernel<<<(NN + 63) / 64, 256, 0, stream>>>(X, packW, bproj, A16, B16);
  phase2_kernel<<<(NE + 127) / 128, 256, 0, stream>>>(A16, B16, eraw, flag,
                                                      packW + 4 * 16384, bmlp,
                                                      out);
}

// Round 5
// 203.079 us; speedup vs baseline: 1.2883x; 1.0740x over previous
//
#include <hip/hip_runtime.h>

#define NN 100000
#define NE 600000
#define DD 128

typedef _Float16 half4_t __attribute__((ext_vector_type(4)));
typedef _Float16 half8_t __attribute__((ext_vector_type(8)));
typedef float f32x4 __attribute__((ext_vector_type(4)));

// XOR-swizzle for [row][256B] f16 LDS tiles (G4). Byte address; flips bits
// 4-6 only, so 8B/16B alignment within a 16B slot is preserved.
__device__ __forceinline__ int swzb(int row, int byte) {
  return row * 256 + (byte ^ ((row & 7) << 4));
}

__device__ __forceinline__ half8_t relu_add(half8_t a, half8_t b) {
  half8_t r;
#pragma unroll
  for (int j = 0; j < 8; ++j) {
    const _Float16 s = a[j] + b[j];
    r[j] = s > (_Float16)0 ? s : (_Float16)0;
  }
  return r;
}

// ---------------------------------------------------------------------------
// Pack 5 weight matrices (128x128 f32, row-major [k][n]) into f16 fragment
// order: packed[m][(nf*4+ks)*64 + l][j] = W[8*(l>>4)+32*ks+j][16*nf+(l&15)].
// (Validated rounds 2-4 as both MFMA operand layouts.)
// m: 0=W_src 1=W_tgt 2=W_proj[:128] 3=W_proj[128:] 4=W_mlp
// ---------------------------------------------------------------------------
__global__ void pack_weights_kernel(const float* __restrict__ Wsrc,
                                    const float* __restrict__ Wtgt,
                                    const float* __restrict__ Wproj,
                                    const float* __restrict__ Wmlp,
                                    _Float16* __restrict__ packed) {
  const int t = (int)blockIdx.x * 256 + (int)threadIdx.x;
  if (t >= 5 * 2048) return;
  const int m = t >> 11;
  const int rem = t & 2047;
  const int nf = rem >> 8;
  const int ks = (rem >> 6) & 3;
  const int l = rem & 63;
  const float* W;
  if (m == 0) W = Wsrc;
  else if (m == 1) W = Wtgt;
  else if (m == 2) W = Wproj;
  else if (m == 3) W = Wproj + 128 * DD;
  else W = Wmlp;
  const int col = (l & 15) + 16 * nf;
  const int k0 = 8 * (l >> 4) + 32 * ks;
  half8_t v;
#pragma unroll
  for (int j = 0; j < 8; ++j) v[j] = (_Float16)W[(size_t)(k0 + j) * DD + col];
  *reinterpret_cast<half8_t*>(packed + (size_t)m * 16384 + (size_t)rem * 8) = v;
}

// ---------------------------------------------------------------------------
// Decode edge_index into int32 idx[2*NE] (idx[0..NE)=src, idx[NE..2NE)=tgt).
// Reference declares int64 but default JAX emits int32; each block detects
// the width itself (ballot over the first 64 odd words: int64 -> all zero).
// ---------------------------------------------------------------------------
__global__ void decode_idx_kernel(const unsigned int* __restrict__ eraw,
                                  int* __restrict__ idx) {
  __shared__ int s_is64;
  const int tid = (int)threadIdx.x;
  if (tid < 64) {
    const unsigned long long b = __ballot(eraw[2 * tid + 1] != 0u);
    if (tid == 0) s_is64 = (b == 0ull) ? 1 : 0;
  }
  __syncthreads();
  const int is64 = s_is64;
  const size_t stride = (size_t)gridDim.x * 256;
  for (size_t i = (size_t)blockIdx.x * 256 + tid; i < 2 * (size_t)NE;
       i += stride)
    idx[i] = (int)(is64 ? eraw[2 * i] : eraw[i]);
}

// ---------------------------------------------------------------------------
// Phase 1: per-node tables (f16 out), swapped-operand MFMA, zero barriers.
//   A[n] = (sigmoid(x W_src) * x) @ W_proj[:128] + b_proj
//   B[n] = (sigmoid(x W_tgt) * x) @ W_proj[128:]
// 64 nodes/block, 4 waves; wave w owns nodes [w*16, w*16+16) (wave-private
// Ts tile). launch_bounds(...,4): cap VGPR at 128 for >=4 waves/SIMD.
// ---------------------------------------------------------------------------
__global__ __launch_bounds__(256, 4)
void phase1_kernel(const float* __restrict__ Xg,
                   const _Float16* __restrict__ packW,
                   const float* __restrict__ bproj,
                   _Float16* __restrict__ Aout,
                   _Float16* __restrict__ Bout) {
  __shared__ _Float16 Ts[64 * DD];
  const int tid = (int)threadIdx.x;
  const int l = tid & 63;
  const int w = tid >> 6;
  const int lr = l & 15;
  const int lg = l >> 4;
  const int nloc = w * 16 + lr;                 // local node id
  const int row0 = (int)blockIdx.x * 64;
  const int ng = row0 + nloc;                   // global node id
  const bool valid = ng < NN;
  const int ngc = valid ? ng : (NN - 1);
  const float* __restrict__ xrow = Xg + (size_t)ngc * DD;

  // hoist the X B-fragments (X^T) across both passes: 32B contiguous / lane
  half8_t xf[4];
#pragma unroll
  for (int ks = 0; ks < 4; ++ks) {
    const f32x4 x0 = *reinterpret_cast<const f32x4*>(xrow + lg * 8 + ks * 32);
    const f32x4 x1 =
        *reinterpret_cast<const f32x4*>(xrow + lg * 8 + ks * 32 + 4);
    half8_t h;
#pragma unroll
    for (int j = 0; j < 4; ++j) {
      h[j] = (_Float16)x0[j];
      h[4 + j] = (_Float16)x1[j];
    }
    xf[ks] = h;
  }

#pragma unroll 1
  for (int p = 0; p < 2; ++p) {
    // ---- GEMM1: S^T = Wg^T X^T ----
    const _Float16* __restrict__ wgb = packW + (size_t)p * 16384 + l * 8;
    f32x4 acc[8];
#pragma unroll
    for (int nf = 0; nf < 8; ++nf) acc[nf] = (f32x4)0.f;
#pragma unroll
    for (int ks = 0; ks < 4; ++ks)
#pragma unroll
      for (int nf = 0; nf < 8; ++nf) {
        const half8_t wf = *reinterpret_cast<const half8_t*>(
            wgb + (size_t)(nf * 4 + ks) * 512);
        acc[nf] =
            __builtin_amdgcn_mfma_f32_16x16x32_f16(wf, xf[ks], acc[nf], 0, 0, 0);
      }

    // ---- T = sigmoid(S) * x  (lane holds S[node=ng][16nf+4lg .. +3]) ----
#pragma unroll
    for (int nf = 0; nf < 8; ++nf) {
      const int c0 = nf * 16 + lg * 4;
      const f32x4 x4 = *reinterpret_cast<const f32x4*>(xrow + c0);
      half4_t th;
#pragma unroll
      for (int j = 0; j < 4; ++j) {
        const float t = x4[j] / (1.f + __expf(-acc[nf][j]));
        th[j] = (_Float16)t;
      }
      *reinterpret_cast<half4_t*>(&Ts[swzb(nloc, c0 * 2) >> 1]) = th;
    }
    // wave-private Ts: compiler-inserted lgkmcnt orders write->read, no barrier

    // ---- GEMM2: table^T = Wp^T T^T ----
    const _Float16* __restrict__ wpb = packW + (size_t)(2 + p) * 16384 + l * 8;
    f32x4 acc2[8];
#pragma unroll
    for (int nf = 0; nf < 8; ++nf) acc2[nf] = (f32x4)0.f;
#pragma unroll
    for (int ks = 0; ks < 4; ++ks) {
      const half8_t tf = *reinterpret_cast<const half8_t*>(
          &Ts[swzb(nloc, lg * 16 + ks * 64) >> 1]);
#pragma unroll
      for (int nf = 0; nf < 8; ++nf) {
        const half8_t wf = *reinterpret_cast<const half8_t*>(
            wpb + (size_t)(nf * 4 + ks) * 512);
        acc2[nf] =
            __builtin_amdgcn_mfma_f32_16x16x32_f16(wf, tf, acc2[nf], 0, 0, 0);
      }
    }

    // ---- store: lane owns table[ng][16nf+4lg .. +3] -> half4 stores ----
    _Float16* __restrict__ dst = p ? Bout : Aout;
    if (valid) {
#pragma unroll
      for (int nf = 0; nf < 8; ++nf) {
        const int c0 = nf * 16 + lg * 4;
        f32x4 v = acc2[nf];
        if (p == 0) {
          const f32x4 bp = *reinterpret_cast<const f32x4*>(bproj + c0);
          v = v + bp;
        }
        half4_t h;
#pragma unroll
        for (int j = 0; j < 4; ++j) h[j] = (_Float16)v[j];
        *reinterpret_cast<half4_t*>(dst + (size_t)ng * DD + c0) = h;
      }
    }
  }
}

// ---------------------------------------------------------------------------
// Phase 2: out[e] = relu(A[src_e] + B[tgt_e]) @ W_mlp + b_mlp   (f32 out)
// Swapped-operand MFMA. W_mlp fragments staged in LDS (32 KB) so the vmcnt
// queue holds ONLY the random table gathers and L1 serves gathers alone.
// 128 edges/block, 4 waves; wave w owns edges [w*32, w*32+32).
// ---------------------------------------------------------------------------
__global__ __launch_bounds__(256, 4)
void phase2_kernel(const _Float16* __restrict__ At,
                   const _Float16* __restrict__ Bt,
                   const int* __restrict__ idx,
                   const _Float16* __restrict__ Wpk,
                   const float* __restrict__ bmlp,
                   float* __restrict__ out) {
  __shared__ _Float16 Wl[16384];  // 32 KB: full packed W_mlp
  const int tid = (int)threadIdx.x;

  // stage W_mlp: 2048 x 16B chunks, contiguous & coalesced
#pragma unroll
  for (int i = 0; i < 8; ++i) {
    const int c = tid + i * 256;
    reinterpret_cast<f32x4*>(Wl)[c] =
        reinterpret_cast<const f32x4*>(Wpk)[c];
  }

  const int l = tid & 63;
  const int w = tid >> 6;
  const int lr = l & 15;
  const int lg = l >> 4;
  const int e0 = (int)blockIdx.x * 128 + w * 32;

  const int er0 = e0 + lr;        // mf = 0 edge
  const int er1 = e0 + 16 + lr;   // mf = 1 edge
  const size_t ec0 = (er0 < NE) ? (size_t)er0 : 0;
  const size_t ec1 = (er1 < NE) ? (size_t)er1 : 0;

  const int ia0 = idx[ec0];
  const int ib0 = idx[(size_t)NE + ec0];
  const int ia1 = idx[ec1];
  const int ib1 = idx[(size_t)NE + ec1];

  const _Float16* __restrict__ pa0 = At + (size_t)ia0 * DD + lg * 8;
  const _Float16* __restrict__ pb0 = Bt + (size_t)ib0 * DD + lg * 8;
  const _Float16* __restrict__ pa1 = At + (size_t)ia1 * DD + lg * 8;
  const _Float16* __restrict__ pb1 = Bt + (size_t)ib1 * DD + lg * 8;

  f32x4 acc[2][8];
#pragma unroll
  for (int mf = 0; mf < 2; ++mf)
#pragma unroll
    for (int nf = 0; nf < 8; ++nf) acc[mf][nf] = (f32x4)0.f;

  // prologue gather (ks = 0)
  half8_t a0 = *reinterpret_cast<const half8_t*>(pa0);
  half8_t b0 = *reinterpret_cast<const half8_t*>(pb0);
  half8_t a1 = *reinterpret_cast<const half8_t*>(pa1);
  half8_t b1 = *reinterpret_cast<const half8_t*>(pb1);

  __syncthreads();  // W_mlp staged

#pragma unroll
  for (int ks = 0; ks < 4; ++ks) {
    half8_t na0, nb0, na1, nb1;
    if (ks < 3) {  // prefetch next ks gathers under this ks's MFMAs
      na0 = *reinterpret_cast<const half8_t*>(pa0 + (ks + 1) * 32);
      nb0 = *reinterpret_cast<const half8_t*>(pb0 + (ks + 1) * 32);
      na1 = *reinterpret_cast<const half8_t*>(pa1 + (ks + 1) * 32);
      nb1 = *reinterpret_cast<const half8_t*>(pb1 + (ks + 1) * 32);
    }
    const half8_t r0 = relu_add(a0, b0);
    const half8_t r1 = relu_add(a1, b1);
#pragma unroll
    for (int nf = 0; nf < 8; ++nf) {
      const half8_t wf = *reinterpret_cast<const half8_t*>(
          &Wl[(size_t)(nf * 4 + ks) * 512 + l * 8]);
      acc[0][nf] =
          __builtin_amdgcn_mfma_f32_16x16x32_f16(wf, r0, acc[0][nf], 0, 0, 0);
      acc[1][nf] =
          __builtin_amdgcn_mfma_f32_16x16x32_f16(wf, r1, acc[1][nf], 0, 0, 0);
    }
    if (ks < 3) { a0 = na0; b0 = nb0; a1 = na1; b1 = nb1; }
  }

  // lane owns out[e][16nf+4lg .. +3] -> float4 nontemporal stores
#pragma unroll
  for (int nf = 0; nf < 8; ++nf) {
    const int c0 = nf * 16 + lg * 4;
    const f32x4 bm = *reinterpret_cast<const f32x4*>(bmlp + c0);
    if (er0 < NE) {
      const f32x4 v = acc[0][nf] + bm;
      __builtin_nontemporal_store(
          v, reinterpret_cast<f32x4*>(out + (size_t)er0 * DD + c0));
    }
    if (er1 < NE) {
      const f32x4 v = acc[1][nf] + bm;
      __builtin_nontemporal_store(
          v, reinterpret_cast<f32x4*>(out + (size_t)er1 * DD + c0));
    }
  }
}

// ---------------------------------------------------------------------------
extern "C" void kernel_launch(void* const* d_in, const int* in_sizes, int n_in,
                              void* d_out, int out_size, void* d_ws,
                              size_t ws_size, hipStream_t stream) {
  (void)in_sizes; (void)n_in; (void)out_size; (void)ws_size;

  const float* X = (const float*)d_in[0];
  const unsigned int* eraw = (const unsigned int*)d_in[1];
  const float* Wsrc = (const float*)d_in[2];
  const float* Wtgt = (const float*)d_in[3];
  const float* Wproj = (const float*)d_in[4];
  const float* bproj = (const float*)d_in[5];
  const float* Wmlp = (const float*)d_in[6];
  const float* bmlp = (const float*)d_in[7];
  float* out = (float*)d_out;

  // ws layout: A16[N*128] f16 | B16[N*128] f16 | packW[5*16384] f16 |
  //            idx[2*NE] int32
  _Float16* A16 = (_Float16*)d_ws;
  _Float16* B16 = A16 + (size_t)NN * DD;
  _Float16* packW = B16 + (size_t)NN * DD;
  int* idx = (int*)(packW + 5 * 16384);

  pack_weights_kernel<<<40, 256, 0, stream>>>(Wsrc, Wtgt, Wproj, Wmlp, packW);
  decode_idx_kernel<<<512, 256, 0, stream>>>(eraw, idx);
  phase1_kernel<<<(NN + 63) / 64, 256, 0, stream>>>(X, packW, bproj, A16, B16);
  phase2_kernel<<<(NE + 127) / 128, 256, 0, stream>>>(A16, B16, idx,
                                                      packW + 4 * 16384, bmlp,
                                                      out);
}

// Round 6
// 174.651 us; speedup vs baseline: 1.4980x; 1.1628x over previous
//
#include <hip/hip_runtime.h>

#define NN 100000
#define NE 600000
#define DD 128

typedef _Float16 half4_t __attribute__((ext_vector_type(4)));
typedef _Float16 half8_t __attribute__((ext_vector_type(8)));
typedef float f32x4 __attribute__((ext_vector_type(4)));

// XOR-swizzle for [row][256B] f16 LDS tiles (G4). Byte address; flips bits
// 4-6 only, so 8B/16B alignment within a 16B slot is preserved.
__device__ __forceinline__ int swzb(int row, int byte) {
  return row * 256 + (byte ^ ((row & 7) << 4));
}

__device__ __forceinline__ half8_t relu_add(half8_t a, half8_t b) {
  half8_t r;
#pragma unroll
  for (int j = 0; j < 8; ++j) {
    const _Float16 s = a[j] + b[j];
    r[j] = s > (_Float16)0 ? s : (_Float16)0;
  }
  return r;
}

// ---------------------------------------------------------------------------
// Pack 5 weight matrices (128x128 f32, row-major [k][n]) into f16 fragment
// order: packed[m][(nf*4+ks)*64 + l][j] = W[8*(l>>4)+32*ks+j][16*nf+(l&15)].
// (Validated rounds 2-5 as both MFMA operand layouts.)
// m: 0=W_src 1=W_tgt 2=W_proj[:128] 3=W_proj[128:] 4=W_mlp
// ---------------------------------------------------------------------------
__global__ void pack_weights_kernel(const float* __restrict__ Wsrc,
                                    const float* __restrict__ Wtgt,
                                    const float* __restrict__ Wproj,
                                    const float* __restrict__ Wmlp,
                                    _Float16* __restrict__ packed) {
  const int t = (int)blockIdx.x * 256 + (int)threadIdx.x;
  if (t >= 5 * 2048) return;
  const int m = t >> 11;
  const int rem = t & 2047;
  const int nf = rem >> 8;
  const int ks = (rem >> 6) & 3;
  const int l = rem & 63;
  const float* W;
  if (m == 0) W = Wsrc;
  else if (m == 1) W = Wtgt;
  else if (m == 2) W = Wproj;
  else if (m == 3) W = Wproj + 128 * DD;
  else W = Wmlp;
  const int col = (l & 15) + 16 * nf;
  const int k0 = 8 * (l >> 4) + 32 * ks;
  half8_t v;
#pragma unroll
  for (int j = 0; j < 8; ++j) v[j] = (_Float16)W[(size_t)(k0 + j) * DD + col];
  *reinterpret_cast<half8_t*>(packed + (size_t)m * 16384 + (size_t)rem * 8) = v;
}

// ---------------------------------------------------------------------------
// Decode edge_index into int32 idx[2*NE] (idx[0..NE)=src, idx[NE..2NE)=tgt).
// Reference declares int64 but default JAX emits int32; each block detects
// the width itself (ballot over the first 64 odd words: int64 -> all zero).
// ---------------------------------------------------------------------------
__global__ void decode_idx_kernel(const unsigned int* __restrict__ eraw,
                                  int* __restrict__ idx) {
  __shared__ int s_is64;
  const int tid = (int)threadIdx.x;
  if (tid < 64) {
    const unsigned long long b = __ballot(eraw[2 * tid + 1] != 0u);
    if (tid == 0) s_is64 = (b == 0ull) ? 1 : 0;
  }
  __syncthreads();
  const int is64 = s_is64;
  const size_t stride = (size_t)gridDim.x * 256;
  for (size_t i = (size_t)blockIdx.x * 256 + tid; i < 2 * (size_t)NE;
       i += stride)
    idx[i] = (int)(is64 ? eraw[2 * i] : eraw[i]);
}

// ---------------------------------------------------------------------------
// Phase 1 (v2): per-node tables (f16 out), swapped-operand MFMA.
//   A[n] = (sigmoid(x W_src) * x) @ W_proj[:128] + b_proj
//   B[n] = (sigmoid(x W_tgt) * x) @ W_proj[128:]
// 64 nodes/block, 4 waves. nf (output cols) SPLIT ACROSS WAVES: wave w owns
// nf in {2w, 2w+1} and keeps those W fragments in REGISTERS (loaded once per
// block) while looping over all 4 node-groups from a shared LDS X tile.
// Cuts per-wave W streaming 16x (128 KB/wave -> 128 KB/block) and makes the
// X global read single + coalesced.
// ---------------------------------------------------------------------------
__global__ __launch_bounds__(256, 4)
void phase1_kernel(const float* __restrict__ Xg,
                   const _Float16* __restrict__ packW,
                   const float* __restrict__ bproj,
                   _Float16* __restrict__ Aout,
                   _Float16* __restrict__ Bout) {
  __shared__ _Float16 Xh[64 * DD];
  __shared__ _Float16 Th[64 * DD];
  const int tid = (int)threadIdx.x;
  const int row0 = (int)blockIdx.x * 64;
  const int rem = NN - row0;
  const int nvalid = rem < 64 ? rem : 64;

  // stage X tile -> f16 LDS (swizzled), coalesced 16B global reads
#pragma unroll
  for (int it = 0; it < 8; ++it) {
    const int i = tid + it * 256;
    const int r = i >> 5;
    const int c4 = i & 31;
    float4 v = make_float4(0.f, 0.f, 0.f, 0.f);
    if (r < nvalid)
      v = reinterpret_cast<const float4*>(Xg + (size_t)(row0 + r) * DD)[c4];
    half4_t h;
    h[0] = (_Float16)v.x; h[1] = (_Float16)v.y;
    h[2] = (_Float16)v.z; h[3] = (_Float16)v.w;
    *reinterpret_cast<half4_t*>(&Xh[swzb(r, c4 * 8) >> 1]) = h;
  }
  __syncthreads();

  const int l = tid & 63;
  const int w = tid >> 6;
  const int lr = l & 15;
  const int lg = l >> 4;

#pragma unroll 1
  for (int p = 0; p < 2; ++p) {
    // ---- W1 fragments for nf = 2w, 2w+1 -> registers (once per pass) ----
    const _Float16* __restrict__ wb1 = packW + (size_t)p * 16384 + l * 8;
    half8_t w1[2][4];
#pragma unroll
    for (int s = 0; s < 2; ++s)
#pragma unroll
      for (int ks = 0; ks < 4; ++ks)
        w1[s][ks] = *reinterpret_cast<const half8_t*>(
            wb1 + (size_t)(((2 * w + s) * 4 + ks)) * 512);

    // ---- GEMM1: S^T slice = W1^T X^T over all 4 node-groups ----
    f32x4 acc[4][2];
#pragma unroll
    for (int mf = 0; mf < 4; ++mf)
#pragma unroll
      for (int s = 0; s < 2; ++s) acc[mf][s] = (f32x4)0.f;
#pragma unroll
    for (int mf = 0; mf < 4; ++mf) {
      half8_t xf[4];
#pragma unroll
      for (int ks = 0; ks < 4; ++ks)
        xf[ks] = *reinterpret_cast<const half8_t*>(
            &Xh[swzb(mf * 16 + lr, lg * 16 + ks * 64) >> 1]);
#pragma unroll
      for (int ks = 0; ks < 4; ++ks)
#pragma unroll
        for (int s = 0; s < 2; ++s)
          acc[mf][s] = __builtin_amdgcn_mfma_f32_16x16x32_f16(
              w1[s][ks], xf[ks], acc[mf][s], 0, 0, 0);
    }

    // pass 1: all waves must finish GEMM2(p=0) reads of Th before overwrite
    if (p) __syncthreads();

    // ---- T = sigmoid(S) * x : lane holds S[mf*16+lr][(2w+s)*16+lg*4+j] ----
#pragma unroll
    for (int mf = 0; mf < 4; ++mf)
#pragma unroll
      for (int s = 0; s < 2; ++s) {
        const int c0 = (2 * w + s) * 16 + lg * 4;
        const int node = mf * 16 + lr;
        const half4_t xh =
            *reinterpret_cast<const half4_t*>(&Xh[swzb(node, c0 * 2) >> 1]);
        half4_t th;
#pragma unroll
        for (int j = 0; j < 4; ++j) {
          const float t = (float)xh[j] / (1.f + __expf(-acc[mf][s][j]));
          th[j] = (_Float16)t;
        }
        *reinterpret_cast<half4_t*>(&Th[swzb(node, c0 * 2) >> 1]) = th;
      }
    __syncthreads();

    // ---- W2 fragments -> registers; GEMM2: table^T slice = W2^T T^T ----
    const _Float16* __restrict__ wb2 = packW + (size_t)(2 + p) * 16384 + l * 8;
    half8_t w2[2][4];
#pragma unroll
    for (int s = 0; s < 2; ++s)
#pragma unroll
      for (int ks = 0; ks < 4; ++ks)
        w2[s][ks] = *reinterpret_cast<const half8_t*>(
            wb2 + (size_t)(((2 * w + s) * 4 + ks)) * 512);

    f32x4 acc2[4][2];
#pragma unroll
    for (int mf = 0; mf < 4; ++mf)
#pragma unroll
      for (int s = 0; s < 2; ++s) acc2[mf][s] = (f32x4)0.f;
#pragma unroll
    for (int mf = 0; mf < 4; ++mf) {
      half8_t tf[4];
#pragma unroll
      for (int ks = 0; ks < 4; ++ks)
        tf[ks] = *reinterpret_cast<const half8_t*>(
            &Th[swzb(mf * 16 + lr, lg * 16 + ks * 64) >> 1]);
#pragma unroll
      for (int ks = 0; ks < 4; ++ks)
#pragma unroll
        for (int s = 0; s < 2; ++s)
          acc2[mf][s] = __builtin_amdgcn_mfma_f32_16x16x32_f16(
              w2[s][ks], tf[ks], acc2[mf][s], 0, 0, 0);
    }

    // ---- store: lane owns table[node][(2w+s)*16+lg*4 .. +3] ----
    _Float16* __restrict__ dst = p ? Bout : Aout;
#pragma unroll
    for (int s = 0; s < 2; ++s) {
      const int c0 = (2 * w + s) * 16 + lg * 4;
      f32x4 bp = (f32x4)0.f;
      if (p == 0) bp = *reinterpret_cast<const f32x4*>(bproj + c0);
#pragma unroll
      for (int mf = 0; mf < 4; ++mf) {
        const int node = mf * 16 + lr;
        if (node < nvalid) {
          const f32x4 v = acc2[mf][s] + bp;
          half4_t h;
#pragma unroll
          for (int j = 0; j < 4; ++j) h[j] = (_Float16)v[j];
          *reinterpret_cast<half4_t*>(dst + (size_t)(row0 + node) * DD + c0) =
              h;
        }
      }
    }
  }
}

// ---------------------------------------------------------------------------
// Phase 2: out[e] = relu(A[src_e] + B[tgt_e]) @ W_mlp + b_mlp   (f32 out)
// Swapped-operand MFMA. W_mlp fragments staged in LDS (32 KB) so the vmcnt
// queue holds ONLY the random table gathers and L1 serves gathers alone.
// 128 edges/block, 4 waves; wave w owns edges [w*32, w*32+32).
// (Unchanged from round 5 for clean attribution of the phase1 change.)
// ---------------------------------------------------------------------------
__global__ __launch_bounds__(256, 4)
void phase2_kernel(const _Float16* __restrict__ At,
                   const _Float16* __restrict__ Bt,
                   const int* __restrict__ idx,
                   const _Float16* __restrict__ Wpk,
                   const float* __restrict__ bmlp,
                   float* __restrict__ out) {
  __shared__ _Float16 Wl[16384];  // 32 KB: full packed W_mlp
  const int tid = (int)threadIdx.x;

  // stage W_mlp: 2048 x 16B chunks, contiguous & coalesced
#pragma unroll
  for (int i = 0; i < 8; ++i) {
    const int c = tid + i * 256;
    reinterpret_cast<f32x4*>(Wl)[c] =
        reinterpret_cast<const f32x4*>(Wpk)[c];
  }

  const int l = tid & 63;
  const int w = tid >> 6;
  const int lr = l & 15;
  const int lg = l >> 4;
  const int e0 = (int)blockIdx.x * 128 + w * 32;

  const int er0 = e0 + lr;        // mf = 0 edge
  const int er1 = e0 + 16 + lr;   // mf = 1 edge
  const size_t ec0 = (er0 < NE) ? (size_t)er0 : 0;
  const size_t ec1 = (er1 < NE) ? (size_t)er1 : 0;

  const int ia0 = idx[ec0];
  const int ib0 = idx[(size_t)NE + ec0];
  const int ia1 = idx[ec1];
  const int ib1 = idx[(size_t)NE + ec1];

  const _Float16* __restrict__ pa0 = At + (size_t)ia0 * DD + lg * 8;
  const _Float16* __restrict__ pb0 = Bt + (size_t)ib0 * DD + lg * 8;
  const _Float16* __restrict__ pa1 = At + (size_t)ia1 * DD + lg * 8;
  const _Float16* __restrict__ pb1 = Bt + (size_t)ib1 * DD + lg * 8;

  f32x4 acc[2][8];
#pragma unroll
  for (int mf = 0; mf < 2; ++mf)
#pragma unroll
    for (int nf = 0; nf < 8; ++nf) acc[mf][nf] = (f32x4)0.f;

  // prologue gather (ks = 0)
  half8_t a0 = *reinterpret_cast<const half8_t*>(pa0);
  half8_t b0 = *reinterpret_cast<const half8_t*>(pb0);
  half8_t a1 = *reinterpret_cast<const half8_t*>(pa1);
  half8_t b1 = *reinterpret_cast<const half8_t*>(pb1);

  __syncthreads();  // W_mlp staged

#pragma unroll
  for (int ks = 0; ks < 4; ++ks) {
    half8_t na0, nb0, na1, nb1;
    if (ks < 3) {  // prefetch next ks gathers under this ks's MFMAs
      na0 = *reinterpret_cast<const half8_t*>(pa0 + (ks + 1) * 32);
      nb0 = *reinterpret_cast<const half8_t*>(pb0 + (ks + 1) * 32);
      na1 = *reinterpret_cast<const half8_t*>(pa1 + (ks + 1) * 32);
      nb1 = *reinterpret_cast<const half8_t*>(pb1 + (ks + 1) * 32);
    }
    const half8_t r0 = relu_add(a0, b0);
    const half8_t r1 = relu_add(a1, b1);
#pragma unroll
    for (int nf = 0; nf < 8; ++nf) {
      const half8_t wf = *reinterpret_cast<const half8_t*>(
          &Wl[(size_t)(nf * 4 + ks) * 512 + l * 8]);
      acc[0][nf] =
          __builtin_amdgcn_mfma_f32_16x16x32_f16(wf, r0, acc[0][nf], 0, 0, 0);
      acc[1][nf] =
          __builtin_amdgcn_mfma_f32_16x16x32_f16(wf, r1, acc[1][nf], 0, 0, 0);
    }
    if (ks < 3) { a0 = na0; b0 = nb0; a1 = na1; b1 = nb1; }
  }

  // lane owns out[e][16nf+4lg .. +3] -> float4 nontemporal stores
#pragma unroll
  for (int nf = 0; nf < 8; ++nf) {
    const int c0 = nf * 16 + lg * 4;
    const f32x4 bm = *reinterpret_cast<const f32x4*>(bmlp + c0);
    if (er0 < NE) {
      const f32x4 v = acc[0][nf] + bm;
      __builtin_nontemporal_store(
          v, reinterpret_cast<f32x4*>(out + (size_t)er0 * DD + c0));
    }
    if (er1 < NE) {
      const f32x4 v = acc[1][nf] + bm;
      __builtin_nontemporal_store(
          v, reinterpret_cast<f32x4*>(out + (size_t)er1 * DD + c0));
    }
  }
}

// ---------------------------------------------------------------------------
extern "C" void kernel_launch(void* const* d_in, const int* in_sizes, int n_in,
                              void* d_out, int out_size, void* d_ws,
                              size_t ws_size, hipStream_t stream) {
  (void)in_sizes; (void)n_in; (void)out_size; (void)ws_size;

  const float* X = (const float*)d_in[0];
  const unsigned int* eraw = (const unsigned int*)d_in[1];
  const float* Wsrc = (const float*)d_in[2];
  const float* Wtgt = (const float*)d_in[3];
  const float* Wproj = (const float*)d_in[4];
  const float* bproj = (const float*)d_in[5];
  const float* Wmlp = (const float*)d_in[6];
  const float* bmlp = (const float*)d_in[7];
  float* out = (float*)d_out;

  // ws layout: A16[N*128] f16 | B16[N*128] f16 | packW[5*16384] f16 |
  //            idx[2*NE] int32
  _Float16* A16 = (_Float16*)d_ws;
  _Float16* B16 = A16 + (size_t)NN * DD;
  _Float16* packW = B16 + (size_t)NN * DD;
  int* idx = (int*)(packW + 5 * 16384);

  pack_weights_kernel<<<40, 256, 0, stream>>>(Wsrc, Wtgt, Wproj, Wmlp, packW);
  decode_idx_kernel<<<512, 256, 0, stream>>>(eraw, idx);
  phase1_kernel<<<(NN + 63) / 64, 256, 0, stream>>>(X, packW, bproj, A16, B16);
  phase2_kernel<<<(NE + 127) / 128, 256, 0, stream>>>(A16, B16, idx,
                                                      packW + 4 * 16384, bmlp,
                                                      out);
}

// Round 7
// 173.713 us; speedup vs baseline: 1.5061x; 1.0054x over previous
//
#include <hip/hip_runtime.h>

#define NN 100000
#define NE 600000
#define DD 128

typedef _Float16 half4_t __attribute__((ext_vector_type(4)));
typedef _Float16 half8_t __attribute__((ext_vector_type(8)));
typedef float f32x4 __attribute__((ext_vector_type(4)));

// XOR-swizzle for [row][256B] f16 LDS tiles (G4). Byte address; flips bits
// 4-6 only, so 8B/16B alignment within a 16B slot is preserved.
__device__ __forceinline__ int swzb(int row, int byte) {
  return row * 256 + (byte ^ ((row & 7) << 4));
}

__device__ __forceinline__ half8_t relu_add(half8_t a, half8_t b) {
  half8_t r;
#pragma unroll
  for (int j = 0; j < 8; ++j) {
    const _Float16 s = a[j] + b[j];
    r[j] = s > (_Float16)0 ? s : (_Float16)0;
  }
  return r;
}

// ---------------------------------------------------------------------------
// Prep kernel (merged: one launch instead of two).
// Blocks [0,40): pack 5 weight matrices (128x128 f32, row-major [k][n]) into
// f16 fragment order:
//   packed[m][(nf*4+ks)*64 + l][j] = W[8*(l>>4)+32*ks+j][16*nf+(l&15)]
// (validated rounds 2-6 as both MFMA operand layouts).
//   m: 0=W_src 1=W_tgt 2=W_proj[:128] 3=W_proj[128:] 4=W_mlp
// Blocks [40,552): decode edge_index into int32 idx[2*NE] (src then tgt).
// Reference declares int64 but default JAX emits int32; each decode block
// detects the width itself (ballot over first 64 odd words: int64 -> all 0).
// ---------------------------------------------------------------------------
__global__ void prep_kernel(const float* __restrict__ Wsrc,
                            const float* __restrict__ Wtgt,
                            const float* __restrict__ Wproj,
                            const float* __restrict__ Wmlp,
                            const unsigned int* __restrict__ eraw,
                            int* __restrict__ idx,
                            _Float16* __restrict__ packed) {
  const int bid = (int)blockIdx.x;
  const int tid = (int)threadIdx.x;
  if (bid < 40) {
    const int t = bid * 256 + tid;
    if (t >= 5 * 2048) return;
    const int m = t >> 11;
    const int rem = t & 2047;
    const int nf = rem >> 8;
    const int ks = (rem >> 6) & 3;
    const int l = rem & 63;
    const float* W;
    if (m == 0) W = Wsrc;
    else if (m == 1) W = Wtgt;
    else if (m == 2) W = Wproj;
    else if (m == 3) W = Wproj + 128 * DD;
    else W = Wmlp;
    const int col = (l & 15) + 16 * nf;
    const int k0 = 8 * (l >> 4) + 32 * ks;
    half8_t v;
#pragma unroll
    for (int j = 0; j < 8; ++j)
      v[j] = (_Float16)W[(size_t)(k0 + j) * DD + col];
    *reinterpret_cast<half8_t*>(packed + (size_t)m * 16384 +
                                (size_t)rem * 8) = v;
  } else {
    __shared__ int s_is64;
    if (tid < 64) {
      const unsigned long long b = __ballot(eraw[2 * tid + 1] != 0u);
      if (tid == 0) s_is64 = (b == 0ull) ? 1 : 0;
    }
    __syncthreads();
    const int is64 = s_is64;
    const size_t stride = (size_t)512 * 256;
    for (size_t i = (size_t)(bid - 40) * 256 + tid; i < 2 * (size_t)NE;
         i += stride)
      idx[i] = (int)(is64 ? eraw[2 * i] : eraw[i]);
  }
}

// ---------------------------------------------------------------------------
// Phase 1 (v2): per-node tables (f16 out), swapped-operand MFMA.
//   A[n] = (sigmoid(x W_src) * x) @ W_proj[:128] + b_proj
//   B[n] = (sigmoid(x W_tgt) * x) @ W_proj[128:]
// 64 nodes/block, 4 waves. nf split across waves; W fragments in registers
// (loaded once per block); all node-groups iterated from a shared LDS X tile.
// ---------------------------------------------------------------------------
__global__ __launch_bounds__(256, 4)
void phase1_kernel(const float* __restrict__ Xg,
                   const _Float16* __restrict__ packW,
                   const float* __restrict__ bproj,
                   _Float16* __restrict__ Aout,
                   _Float16* __restrict__ Bout) {
  __shared__ _Float16 Xh[64 * DD];
  __shared__ _Float16 Th[64 * DD];
  const int tid = (int)threadIdx.x;
  const int row0 = (int)blockIdx.x * 64;
  const int rem = NN - row0;
  const int nvalid = rem < 64 ? rem : 64;

  // stage X tile -> f16 LDS (swizzled), coalesced 16B global reads
#pragma unroll
  for (int it = 0; it < 8; ++it) {
    const int i = tid + it * 256;
    const int r = i >> 5;
    const int c4 = i & 31;
    float4 v = make_float4(0.f, 0.f, 0.f, 0.f);
    if (r < nvalid)
      v = reinterpret_cast<const float4*>(Xg + (size_t)(row0 + r) * DD)[c4];
    half4_t h;
    h[0] = (_Float16)v.x; h[1] = (_Float16)v.y;
    h[2] = (_Float16)v.z; h[3] = (_Float16)v.w;
    *reinterpret_cast<half4_t*>(&Xh[swzb(r, c4 * 8) >> 1]) = h;
  }
  __syncthreads();

  const int l = tid & 63;
  const int w = tid >> 6;
  const int lr = l & 15;
  const int lg = l >> 4;

#pragma unroll 1
  for (int p = 0; p < 2; ++p) {
    // ---- W1 fragments for nf = 2w, 2w+1 -> registers (once per pass) ----
    const _Float16* __restrict__ wb1 = packW + (size_t)p * 16384 + l * 8;
    half8_t w1[2][4];
#pragma unroll
    for (int s = 0; s < 2; ++s)
#pragma unroll
      for (int ks = 0; ks < 4; ++ks)
        w1[s][ks] = *reinterpret_cast<const half8_t*>(
            wb1 + (size_t)(((2 * w + s) * 4 + ks)) * 512);

    // ---- GEMM1: S^T slice = W1^T X^T over all 4 node-groups ----
    f32x4 acc[4][2];
#pragma unroll
    for (int mf = 0; mf < 4; ++mf)
#pragma unroll
      for (int s = 0; s < 2; ++s) acc[mf][s] = (f32x4)0.f;
#pragma unroll
    for (int mf = 0; mf < 4; ++mf) {
      half8_t xf[4];
#pragma unroll
      for (int ks = 0; ks < 4; ++ks)
        xf[ks] = *reinterpret_cast<const half8_t*>(
            &Xh[swzb(mf * 16 + lr, lg * 16 + ks * 64) >> 1]);
#pragma unroll
      for (int ks = 0; ks < 4; ++ks)
#pragma unroll
        for (int s = 0; s < 2; ++s)
          acc[mf][s] = __builtin_amdgcn_mfma_f32_16x16x32_f16(
              w1[s][ks], xf[ks], acc[mf][s], 0, 0, 0);
    }

    // pass 1: all waves must finish GEMM2(p=0) reads of Th before overwrite
    if (p) __syncthreads();

    // ---- T = sigmoid(S) * x : lane holds S[mf*16+lr][(2w+s)*16+lg*4+j] ----
#pragma unroll
    for (int mf = 0; mf < 4; ++mf)
#pragma unroll
      for (int s = 0; s < 2; ++s) {
        const int c0 = (2 * w + s) * 16 + lg * 4;
        const int node = mf * 16 + lr;
        const half4_t xh =
            *reinterpret_cast<const half4_t*>(&Xh[swzb(node, c0 * 2) >> 1]);
        half4_t th;
#pragma unroll
        for (int j = 0; j < 4; ++j) {
          const float t = (float)xh[j] / (1.f + __expf(-acc[mf][s][j]));
          th[j] = (_Float16)t;
        }
        *reinterpret_cast<half4_t*>(&Th[swzb(node, c0 * 2) >> 1]) = th;
      }
    __syncthreads();

    // ---- W2 fragments -> registers; GEMM2: table^T slice = W2^T T^T ----
    const _Float16* __restrict__ wb2 = packW + (size_t)(2 + p) * 16384 + l * 8;
    half8_t w2[2][4];
#pragma unroll
    for (int s = 0; s < 2; ++s)
#pragma unroll
      for (int ks = 0; ks < 4; ++ks)
        w2[s][ks] = *reinterpret_cast<const half8_t*>(
            wb2 + (size_t)(((2 * w + s) * 4 + ks)) * 512);

    f32x4 acc2[4][2];
#pragma unroll
    for (int mf = 0; mf < 4; ++mf)
#pragma unroll
      for (int s = 0; s < 2; ++s) acc2[mf][s] = (f32x4)0.f;
#pragma unroll
    for (int mf = 0; mf < 4; ++mf) {
      half8_t tf[4];
#pragma unroll
      for (int ks = 0; ks < 4; ++ks)
        tf[ks] = *reinterpret_cast<const half8_t*>(
            &Th[swzb(mf * 16 + lr, lg * 16 + ks * 64) >> 1]);
#pragma unroll
      for (int ks = 0; ks < 4; ++ks)
#pragma unroll
        for (int s = 0; s < 2; ++s)
          acc2[mf][s] = __builtin_amdgcn_mfma_f32_16x16x32_f16(
              w2[s][ks], tf[ks], acc2[mf][s], 0, 0, 0);
    }

    // ---- store: lane owns table[node][(2w+s)*16+lg*4 .. +3] ----
    _Float16* __restrict__ dst = p ? Bout : Aout;
#pragma unroll
    for (int s = 0; s < 2; ++s) {
      const int c0 = (2 * w + s) * 16 + lg * 4;
      f32x4 bp = (f32x4)0.f;
      if (p == 0) bp = *reinterpret_cast<const f32x4*>(bproj + c0);
#pragma unroll
      for (int mf = 0; mf < 4; ++mf) {
        const int node = mf * 16 + lr;
        if (node < nvalid) {
          const f32x4 v = acc2[mf][s] + bp;
          half4_t h;
#pragma unroll
          for (int j = 0; j < 4; ++j) h[j] = (_Float16)v[j];
          *reinterpret_cast<half4_t*>(dst + (size_t)(row0 + node) * DD + c0) =
              h;
        }
      }
    }
  }
}

// ---------------------------------------------------------------------------
// Phase 2 (v3): out[e] = relu(A[src_e] + B[tgt_e]) @ W_mlp + b_mlp (f32 out)
// Swapped-operand MFMA; W_mlp fragments in LDS (32 KB). MLP-maximized: one
// m-frag per wave (16 edges), ALL 8 table gathers issued upfront and drained
// once at the W-staging barrier; MFMA loop then has zero VMEM waits.
// 64 edges/block (600000 = 9375*64 exact), 4 waves.
// launch_bounds(256,5): VGPR cap 102 -> 5 waves/SIMD (LDS -> 5 blocks/CU).
// ---------------------------------------------------------------------------
__global__ __launch_bounds__(256, 5)
void phase2_kernel(const _Float16* __restrict__ At,
                   const _Float16* __restrict__ Bt,
                   const int* __restrict__ idx,
                   const _Float16* __restrict__ Wpk,
                   const float* __restrict__ bmlp,
                   float* __restrict__ out) {
  __shared__ _Float16 Wl[16384];  // 32 KB: full packed W_mlp
  const int tid = (int)threadIdx.x;
  const int l = tid & 63;
  const int w = tid >> 6;
  const int lr = l & 15;
  const int lg = l >> 4;
  const int er = (int)blockIdx.x * 64 + w * 16 + lr;  // this lane's edge

  // issue the dependent idx -> gather chain FIRST (starts at T0)
  const int ia = idx[er];
  const int ib = idx[(size_t)NE + er];
  const _Float16* __restrict__ pa = At + (size_t)ia * DD + lg * 8;
  const _Float16* __restrict__ pb = Bt + (size_t)ib * DD + lg * 8;
  half8_t af[4], bf[4];
#pragma unroll
  for (int ks = 0; ks < 4; ++ks) {
    af[ks] = *reinterpret_cast<const half8_t*>(pa + ks * 32);
    bf[ks] = *reinterpret_cast<const half8_t*>(pb + ks * 32);
  }

  // stage W_mlp: 2048 x 16B chunks, contiguous & coalesced (overlaps gathers)
#pragma unroll
  for (int i = 0; i < 8; ++i) {
    const int c = tid + i * 256;
    reinterpret_cast<f32x4*>(Wl)[c] = reinterpret_cast<const f32x4*>(Wpk)[c];
  }

  f32x4 acc[8];
#pragma unroll
  for (int nf = 0; nf < 8; ++nf) acc[nf] = (f32x4)0.f;

  __syncthreads();  // drains vmcnt once: gathers + W loads all in flight

#pragma unroll
  for (int ks = 0; ks < 4; ++ks) {
    const half8_t r = relu_add(af[ks], bf[ks]);
#pragma unroll
    for (int nf = 0; nf < 8; ++nf) {
      const half8_t wf = *reinterpret_cast<const half8_t*>(
          &Wl[(size_t)(nf * 4 + ks) * 512 + l * 8]);
      acc[nf] =
          __builtin_amdgcn_mfma_f32_16x16x32_f16(wf, r, acc[nf], 0, 0, 0);
    }
  }

  // lane owns out[er][16nf+4lg .. +3] -> float4 nontemporal stores
#pragma unroll
  for (int nf = 0; nf < 8; ++nf) {
    const int c0 = nf * 16 + lg * 4;
    const f32x4 bm = *reinterpret_cast<const f32x4*>(bmlp + c0);
    const f32x4 v = acc[nf] + bm;
    __builtin_nontemporal_store(
        v, reinterpret_cast<f32x4*>(out + (size_t)er * DD + c0));
  }
}

// ---------------------------------------------------------------------------
extern "C" void kernel_launch(void* const* d_in, const int* in_sizes, int n_in,
                              void* d_out, int out_size, void* d_ws,
                              size_t ws_size, hipStream_t stream) {
  (void)in_sizes; (void)n_in; (void)out_size; (void)ws_size;

  const float* X = (const float*)d_in[0];
  const unsigned int* eraw = (const unsigned int*)d_in[1];
  const float* Wsrc = (const float*)d_in[2];
  const float* Wtgt = (const float*)d_in[3];
  const float* Wproj = (const float*)d_in[4];
  const float* bproj = (const float*)d_in[5];
  const float* Wmlp = (const float*)d_in[6];
  const float* bmlp = (const float*)d_in[7];
  float* out = (float*)d_out;

  // ws layout: A16[N*128] f16 | B16[N*128] f16 | packW[5*16384] f16 |
  //            idx[2*NE] int32
  _Float16* A16 = (_Float16*)d_ws;
  _Float16* B16 = A16 + (size_t)NN * DD;
  _Float16* packW = B16 + (size_t)NN * DD;
  int* idx = (int*)(packW + 5 * 16384);

  prep_kernel<<<552, 256, 0, stream>>>(Wsrc, Wtgt, Wproj, Wmlp, eraw, idx,
                                       packW);
  phase1_kernel<<<(NN + 63) / 64, 256, 0, stream>>>(X, packW, bproj, A16, B16);
  phase2_kernel<<<NE / 64, 256, 0, stream>>>(A16, B16, idx,
                                             packW + 4 * 16384, bmlp, out);
}